// Round 6
// baseline (315.424 us; speedup 1.0000x reference)
//
#include <hip/hip_runtime.h>
#include <math.h>

// Problem constants
#define BB 16
#define C1 256     // in/out channels of the block
#define CHD 128    // hidden channels
#define NN 4096    // H*W
#define INV_T (1.0f/16.0f)   // TEMPERATURE = sqrt(256) = 16

typedef _Float16 half8 __attribute__((ext_vector_type(8)));
typedef __attribute__((ext_vector_type(4))) float f32x4;
typedef __attribute__((ext_vector_type(16))) float f32x16;

__device__ inline unsigned short f2h(float f) {
    _Float16 h = (_Float16)f;            // RN conversion
    return __builtin_bit_cast(unsigned short, h);
}

// async global->LDS, 16B per lane; LDS dest = wave-uniform base + lane*16
#define GLDS(g, l) __builtin_amdgcn_global_load_lds(                              \
    (const __attribute__((address_space(1))) unsigned int*)(g),                   \
    (__attribute__((address_space(3))) unsigned int*)(l), 16, 0, 0)

// XCD-chunked bijective blockIdx swizzle (T1). Requires nwg % 8 == 0.
__device__ inline void xcd_remap(int& bx, int& by, int& bz) {
    int gx = gridDim.x, gy = gridDim.y;
    int lin = blockIdx.x + gx * (blockIdx.y + gy * blockIdx.z);
    int cpx = (gx * gy * (int)gridDim.z) >> 3;
    lin = (lin & 7) * cpx + (lin >> 3);
    bx = lin % gx; int t = lin / gx; by = t % gy; bz = t / gy;
}

// ---------------------------------------------------------------------------
// NCHW fp32 -> CHUNKED half-split padded NHWC fp16:
// xh[b][ck=c/16][hp][cihalf(2)][w(64)][8ci], hp in [0,66), rows 0 & 65 zero.
// ---------------------------------------------------------------------------
__global__ __launch_bounds__(256) void nchw_to_nhwc_f16(
    const float* __restrict__ x, unsigned short* __restrict__ xh, int C)
{
    const int c0 = blockIdx.x * 64;
    const int hp = blockIdx.y;
    const int b  = blockIdx.z;
    const int nCk = C >> 4;

    if (hp == 0 || hp == 65) {
        for (int idx = threadIdx.x; idx < 1024; idx += 256) {
            int w = idx >> 4, cq = (idx & 15) * 4;
            int ck = (c0 >> 4) + (cq >> 4), half = (cq >> 3) & 1, rem = cq & 7;
            ushort4 z; z.x = z.y = z.z = z.w = 0;
            *(ushort4*)&xh[(((((size_t)b * nCk + ck) * 66 + hp) * 2 + half) * 64 + w) * 8
                           + rem] = z;
        }
        return;
    }
    const int h = hp - 1;
    __shared__ float ts[64][65];
    for (int idx = threadIdx.x; idx < 4096; idx += 256) {
        int cl = idx >> 6, w = idx & 63;
        ts[cl][w] = x[(((size_t)b * C + c0 + cl) * 64 + h) * 64 + w];
    }
    __syncthreads();
    for (int idx = threadIdx.x; idx < 1024; idx += 256) {
        int w = idx >> 4, cq = (idx & 15) * 4;
        int ck = (c0 >> 4) + (cq >> 4), half = (cq >> 3) & 1, rem = cq & 7;
        ushort4 o;
        o.x = f2h(ts[cq + 0][w]); o.y = f2h(ts[cq + 1][w]);
        o.z = f2h(ts[cq + 2][w]); o.w = f2h(ts[cq + 3][w]);
        *(ushort4*)&xh[(((((size_t)b * nCk + ck) * 66 + hp) * 2 + half) * 64 + w) * 8
                       + rem] = o;
    }
}

// ---------------------------------------------------------------------------
// Pack conv weights [Cout][Cin][3][3] fp32 -> [ck][kk][cihalf][Cout][8ci] fp16
// (per-(ck,kk,half) the co window is contiguous -> conv reads A-frags as
// perfectly coalesced 16B/lane DIRECT global loads, no LDS round-trip)
// ---------------------------------------------------------------------------
__global__ __launch_bounds__(256) void pack_w_kernel(
    const float* __restrict__ w, unsigned short* __restrict__ wT, int Cout, int Cin)
{
    int idx = blockIdx.x * 256 + threadIdx.x;
    int total = Cout * Cin * 9;
    if (idx >= total) return;
    int ci = idx % Cin; int t = idx / Cin; int co = t % Cout; int kk = t / Cout;
    int ck = ci >> 4, half = (ci >> 3) & 1, rem = ci & 7;
    wT[((((size_t)ck * 9 + kk) * 2 + half) * Cout + co) * 8 + rem] =
        f2h(w[((size_t)co * Cin + ci) * 9 + kk]);
}

// ---------------------------------------------------------------------------
// Zero the pad rows (0 and 65) of chunked y1h [B][8ck][66][2][64][8]
// ---------------------------------------------------------------------------
__global__ __launch_bounds__(256) void zero_y1h_pads(unsigned short* __restrict__ y1h)
{
    int idx = blockIdx.x * 256 + threadIdx.x;   // 65536 ushort4 stores
    int b   = idx >> 12;
    int ck  = (idx >> 9) & 7;
    int row = ((idx >> 8) & 1) ? 65 : 0;
    int inner = (idx & 255) * 4;                 // 0..1020 step 4
    ushort4 z; z.x = z.y = z.z = z.w = 0;
    *(ushort4*)&y1h[(((size_t)b * 8 + ck) * 66 + row) * 1024 + inner] = z;
}

// ---------------------------------------------------------------------------
// Implicit-GEMM conv3x3 + BN + SiLU via fp16 MFMA (fp32 accumulate).
// 512 threads = 8 waves; wave w -> output row h0+w as 2x2 tiles of
// mfma_f32_32x32x16_f16. ci chunked by 16, double-buffered xs-only LDS,
// prefetch before compute, one barrier per chunk.
// NEW (R6): A-fragments (weights) are loaded DIRECTLY global->VGPR from
// the [ck][kk][half][co][8ci] layout (coalesced 512B per half-wave,
// L1-resident 18KB/chunk, shared by all waves) -- removing the weight
// LDS round-trip halves ds_read_b128 traffic (the measured binding
// resource: 576 reads x 12cy = 6.9k cy/chunk/CU vs MFMA 1.16k) and
// drops LDS to 66KB. B-frags stay in conflict-free half-split LDS.
// conv1: outNHWC != nullptr -> chunked half-split NHWC y1h.
// conv2: yhi NCHW fp16 + yhiT chunked [b][ck][n][16d].
// grid: (Cout/64, 8, B), block 512.
// ---------------------------------------------------------------------------
__global__ __launch_bounds__(512, 4) void conv_mfma_kernel(
    const unsigned short* __restrict__ xh, const unsigned short* __restrict__ wT,
    const float* __restrict__ gamma, const float* __restrict__ beta,
    const float* __restrict__ mean, const float* __restrict__ var,
    unsigned short* __restrict__ outNHWC,
    unsigned short* __restrict__ yhi, unsigned short* __restrict__ yhiT,
    int Cin, int Cout)
{
    int bx, by, bz;
    xcd_remap(bx, by, bz);
    const int tid  = threadIdx.x;
    const int wid  = tid >> 6;          // 0..7, wave -> output row h0+wid
    const int lane = tid & 63;
    const int l31  = lane & 31;
    const int hi   = lane >> 5;
    const int coBase = bx * 64;
    const int h0     = by * 8;
    const int b      = bz;
    const int nCk    = Cin >> 4;

    // xs double buffer: [row 0..9][cihalf][col 0..65][8ci] = 10560 shorts/buf
    // epilogue reuses smem[0..32767] as os[8 row][64 w][64 co] (swizzled)
    __shared__ __align__(16) unsigned short smem[32768];   // 64 KB
    __shared__ float bnsc[64], bnsh[64];

    if (tid < 64) {
        int co = coBase + tid;
        float sc = gamma[co] * rsqrtf(var[co] + 1e-5f);
        bnsc[tid] = sc;
        bnsh[tid] = beta[co] - mean[co] * sc;
    }
    if (tid < 80) {   // zero halo cols 0 and 65: 2 buf x 10 row x 2 half x 2 col
        int buf  = tid & 1;
        int col  = ((tid >> 1) & 1) ? 65 : 0;
        int half = (tid >> 2) & 1;
        int r    = tid >> 3;               // 0..9
        ushort4 z; z.x = z.y = z.z = z.w = 0;
        *(ushort4*)&smem[buf * 10560 + ((r * 2 + half) * 66 + col) * 8] = z;
        *(ushort4*)&smem[buf * 10560 + ((r * 2 + half) * 66 + col) * 8 + 4] = z;
    }

    // stage one 16-ci chunk of activations: 20 issues, all 1KB contiguous
    auto stage = [&](int sel, int ck) {
        unsigned short* xsd = smem + sel * 10560;
        for (int it = wid; it < 20; it += 8) {
            int r = it >> 1, half = it & 1;
            const unsigned short* g =
                xh + ((((size_t)b * nCk + ck) * 66 + h0 + r) * 2 + half) * 512 + lane * 8;
            GLDS(g, xsd + ((r * 2 + half) * 66 + 1) * 8);
        }
    };

    stage(0, 0);
    __syncthreads();

    f32x16 acc[2][2] = {};
    const size_t kkStride = (size_t)2 * Cout * 8;   // shorts per kk step

    int sel = 0;
    for (int ck = 0; ck < nCk; ck++) {
        if (ck + 1 < nCk) stage(sel ^ 1, ck + 1);   // prefetch next chunk

        const unsigned short* xsb = smem + sel * 10560;
        // per-lane weight base for this chunk: [ck][kk=0][hi][coBase+l31][0]
        const unsigned short* wA =
            wT + (((size_t)ck * 18 + hi) * Cout + coBase + l31) * 8;

        half8 a0c = *(const half8*)&wA[0];
        half8 a1c = *(const half8*)&wA[256];        // +32 co
        __builtin_amdgcn_s_setprio(1);
#pragma unroll
        for (int kk = 0; kk < 9; kk++) {
            const int kh = kk / 3, kw = kk % 3;
            half8 a0n = a0c, a1n = a1c;
            if (kk < 8) {                            // prefetch next kk's A
                a0n = *(const half8*)&wA[(kk + 1) * kkStride];
                a1n = *(const half8*)&wA[(kk + 1) * kkStride + 256];
            }
            const unsigned short* xr =
                &xsb[(((wid + kh) * 2 + hi) * 66 + l31 + kw) * 8];
            half8 b0 = *(const half8*)xr;
            half8 b1 = *(const half8*)&xr[32 * 8];
            acc[0][0] = __builtin_amdgcn_mfma_f32_32x32x16_f16(a0c, b0, acc[0][0], 0, 0, 0);
            acc[0][1] = __builtin_amdgcn_mfma_f32_32x32x16_f16(a0c, b1, acc[0][1], 0, 0, 0);
            acc[1][0] = __builtin_amdgcn_mfma_f32_32x32x16_f16(a1c, b0, acc[1][0], 0, 0, 0);
            acc[1][1] = __builtin_amdgcn_mfma_f32_32x32x16_f16(a1c, b1, acc[1][1], 0, 0, 0);
            a0c = a0n; a1c = a1n;
        }
        __builtin_amdgcn_s_setprio(0);
        __syncthreads();   // next buffer staged + this buffer free to overwrite
        sel ^= 1;
    }

    // --------------------------------------------------------------
    // Epilogue. D layout (32x32): col=lane&31 -> w,
    // row = (reg&3) + 8*(reg>>2) + 4*hi -> co.
    // Stage BN+SiLU fp16 results into os[row][w][co] with XOR swizzle
    // ((w+row)&7)<<3 on the co-offset, then dense 1KB chunked writes.
    // --------------------------------------------------------------
    const int orow = h0 + wid;
    const bool isConv1 = (outNHWC != nullptr);

    __syncthreads();   // all K-loop LDS reads done before overwrite

#pragma unroll
    for (int mi = 0; mi < 2; mi++)
#pragma unroll
        for (int ni = 0; ni < 2; ni++) {
            f32x16 a = acc[mi][ni];
            int w = ni * 32 + l31;
            int swz = ((l31 + wid) & 7) << 3;
#pragma unroll
            for (int rq = 0; rq < 4; rq++) {
                int c0 = mi * 32 + rq * 8 + hi * 4;   // local co base
                ushort4 o; unsigned short* op = (unsigned short*)&o;
#pragma unroll
                for (int r = 0; r < 4; r++) {
                    float t = a[rq * 4 + r] * bnsc[c0 + r] + bnsh[c0 + r];
                    float s = t / (1.f + __expf(-t));
                    op[r] = f2h(s);
                    if (!isConv1)
                        yhi[(((size_t)b * Cout + coBase + c0 + r) * 64 + orow) * 64 + w] = op[r];
                }
                *(ushort4*)&smem[wid * 4096 + w * 64 + (c0 ^ swz)] = o;
            }
        }
    __syncthreads();

    // dense write-out: 4096 16B units = [ck(4)][row(8)][w(64)][s(2)];
    // unit g = j*512 + tid -> each instruction writes 1KB contiguous.
    const int ckB = bx * 4;   // output chunk base
    const int nCkOut = Cout >> 4;
#pragma unroll
    for (int j = 0; j < 8; j++) {
        int g   = j * 512 + tid;
        int s   = g & 1;
        int w   = (g >> 1) & 63;
        int row = (g >> 7) & 7;
        int ck  = g >> 10;
        uint4 v = *(const uint4*)&smem[row * 4096 + w * 64 +
                     (((ck * 2 + s) * 8) ^ (((w + row) & 7) << 3))];
        if (isConv1) {
            // y1h [b][ck][hp][cihalf=s][w][8]
            *(uint4*)&outNHWC[((((((size_t)b * nCkOut + ckB + ck) * 66 + h0 + row + 1) * 2 + s)
                               * 64 + w) * 8)] = v;
        } else {
            // yhiT [b][ck][n][16d] (byte-identical to [n][half][8])
            *(uint4*)&yhiT[(((size_t)b * nCkOut + ckB + ck) * 4096 + (size_t)(h0 + row) * 64 + w) * 16
                           + s * 8] = v;
        }
    }
}

// ---------------------------------------------------------------------------
// scores = (y . y^T)/16, fp16 MFMA, SYMMETRIC: only upper-triangle 64x64 tile
// pairs computed (10 of 16); each writes its tile and the transpose.
// SPLIT-K x2: blockIdx.y = kh selects n-half; partials summed in softmax.
// grid: (10, 2, 16)
// ---------------------------------------------------------------------------
__global__ __launch_bounds__(256) void scores_mfma_kernel(
    const unsigned short* __restrict__ yhi, float* __restrict__ scores)
{
    static const int TI[10] = {0,0,0,0,1,1,1,2,2,3};
    static const int TJ[10] = {0,1,2,3,1,2,3,2,3,3};
    int bx, by, bz;
    xcd_remap(bx, by, bz);
    const int b  = bz;
    const int kh = by;
    const int ti = TI[bx], tj = TJ[bx];
    const int cB = ti * 64;
    const int dB = tj * 64;
    const int tid  = threadIdx.x;
    const int wid  = tid >> 6;
    const int lane = tid & 63;
    const int ln   = lane & 15;
    const int q    = lane >> 4;
    const int wm   = wid >> 1, wn = wid & 1;

    float* scp = scores + (size_t)kh * 1048576;   // partial buffer for this half

    __shared__ unsigned short As[64 * 128];  // 16 KB, rows cB..cB+63, swizzled
    __shared__ unsigned short Bs[64 * 128];  // 16 KB, rows dB..dB+63, swizzled

    const int rl = lane >> 4;
    const int gl = lane & 15;

    f32x4 acc[2][2] = {};

    for (int ck = kh * 16; ck < kh * 16 + 16; ck++) {
        const int n0 = ck * 128;
        for (int it = wid; it < 32; it += 4) {
            const int tile = it >> 4;
            const int j = it & 15;
            const int r = j * 4 + rl;
            const int gq = gl ^ (r & 7);
            const int rowAbs = (tile ? dB : cB) + r;
            const unsigned short* g =
                yhi + ((size_t)b * 256 + rowAbs) * 4096 + n0 + gq * 8;
            GLDS(g, (tile ? Bs : As) + j * 512);
        }
        __syncthreads();

#pragma unroll
        for (int kwin = 0; kwin < 4; kwin++) {
            half8 ah[2], bh[2];
#pragma unroll
            for (int mi = 0; mi < 2; mi++) {
                int row = wm * 32 + mi * 16 + ln;
                ah[mi] = *(const half8*)&As[row * 128 + ((kwin * 4 + q) ^ (ln & 7)) * 8];
            }
#pragma unroll
            for (int ni = 0; ni < 2; ni++) {
                int row = wn * 32 + ni * 16 + ln;
                bh[ni] = *(const half8*)&Bs[row * 128 + ((kwin * 4 + q) ^ (ln & 7)) * 8];
            }
#pragma unroll
            for (int mi = 0; mi < 2; mi++)
#pragma unroll
                for (int ni = 0; ni < 2; ni++)
                    acc[mi][ni] = __builtin_amdgcn_mfma_f32_16x16x32_f16(
                        ah[mi], bh[ni], acc[mi][ni], 0, 0, 0);
        }
        __syncthreads();
    }

#pragma unroll
    for (int mi = 0; mi < 2; mi++)
#pragma unroll
        for (int ni = 0; ni < 2; ni++) {
            f32x4 a = acc[mi][ni];
            float vals[4];
            vals[0] = a.x * INV_T; vals[1] = a.y * INV_T;
            vals[2] = a.z * INV_T; vals[3] = a.w * INV_T;
            int c0 = cB + wm * 32 + mi * 16 + q * 4;
            int d  = dB + wn * 32 + ni * 16 + ln;
#pragma unroll
            for (int r = 0; r < 4; r++)
                scp[((size_t)b * C1 + c0 + r) * C1 + d] = vals[r];
            if (ti != tj) {   // mirror tile
                float4 tv = {vals[0], vals[1], vals[2], vals[3]};
                *(float4*)&scp[((size_t)b * C1 + d) * C1 + c0] = tv;
            }
        }
}

// ---------------------------------------------------------------------------
// Row softmax over 256 entries; sums the two split-K partial fp32 buffers,
// writes fp16 attn.
// ---------------------------------------------------------------------------
__global__ __launch_bounds__(64) void softmax_kernel(
    const float* __restrict__ scores, unsigned short* __restrict__ attn16)
{
    const int row = blockIdx.x;
    const float* p = scores + (size_t)row * C1;
    const int lane = threadIdx.x;

    float4 v0 = ((const float4*)p)[lane];
    float4 v1 = ((const float4*)(p + 1048576))[lane];
    float4 v;
    v.x = v0.x + v1.x; v.y = v0.y + v1.y;
    v.z = v0.z + v1.z; v.w = v0.w + v1.w;
    float m = fmaxf(fmaxf(v.x, v.y), fmaxf(v.z, v.w));
#pragma unroll
    for (int off = 32; off >= 1; off >>= 1)
        m = fmaxf(m, __shfl_xor(m, off, 64));

    float4 e;
    e.x = expf(v.x - m); e.y = expf(v.y - m);
    e.z = expf(v.z - m); e.w = expf(v.w - m);
    float s = e.x + e.y + e.z + e.w;
#pragma unroll
    for (int off = 32; off >= 1; off >>= 1)
        s += __shfl_xor(s, off, 64);
    float inv = 1.f / s;
    ushort4 o;
    o.x = f2h(e.x * inv); o.y = f2h(e.y * inv);
    o.z = f2h(e.z * inv); o.w = f2h(e.w * inv);
    *(ushort4*)&attn16[(size_t)row * C1 + lane * 4] = o;
}

// ---------------------------------------------------------------------------
// out[b][c][n] = x[b][c][n] + sum_d attn[c][d] * y[d][n]  via fp16 MFMA.
// A = attn16 [b][c][d] (k=d contiguous); B = yhiT CHUNKED [b][d/16][n][16d].
// Block tile 64c x 128n, 4 waves of 32x64. K-chunks of 64 (4 chunks).
// grid: (32, 4, 16)
// ---------------------------------------------------------------------------
__global__ __launch_bounds__(256) void out_mfma_kernel(
    const unsigned short* __restrict__ attn16, const unsigned short* __restrict__ yhiT,
    const float* __restrict__ x, float* __restrict__ out)
{
    int bx, by, bz;
    xcd_remap(bx, by, bz);
    const int b  = bz;
    const int cB = by * 64;
    const int nB = bx * 128;
    const int tid  = threadIdx.x;
    const int wid  = tid >> 6;
    const int lane = tid & 63;
    const int ln   = lane & 15;
    const int q    = lane >> 4;
    const int wm   = wid >> 1, wn = wid & 1;

    __shared__ unsigned short As[64 * 64];    //  8 KB, XOR-swizzled
    __shared__ unsigned short Bs[4 * 128 * 16];   // 16 KB: [u(4 d-sub)][128 n][16d]

    const int r8 = lane >> 3;
    const int gq = (lane & 7) ^ r8;

    f32x4 acc[2][4] = {};

    for (int ck = 0; ck < 4; ck++) {
        const int d0 = ck * 64;
        for (int it = wid; it < 24; it += 4) {
            if (it < 8) {
                const unsigned short* g =
                    attn16 + ((size_t)b * 256 + cB + it * 8 + r8) * 256 + d0 + gq * 8;
                GLDS(g, As + it * 512);
            } else {
                int j = it - 8;            // 0..15
                int u = j >> 2, part = j & 3;
                const unsigned short* g =
                    yhiT + (((size_t)b * 16 + ck * 4 + u) * 4096 + nB + part * 32) * 16 + lane * 8;
                GLDS(g, Bs + (u * 128 + part * 32) * 16);
            }
        }
        __syncthreads();

#pragma unroll
        for (int kwin = 0; kwin < 2; kwin++) {
            const int cc = (((kwin * 4 + q) ^ (ln & 7))) * 8;
            const int gK = kwin * 4 + q;
            half8 af[2], bfr[4];
#pragma unroll
            for (int mi = 0; mi < 2; mi++)
                af[mi] = *(const half8*)&As[(wm * 32 + mi * 16 + ln) * 64 + cc];
#pragma unroll
            for (int ni = 0; ni < 4; ni++) {
                int row = wn * 64 + ni * 16 + ln;
                bfr[ni] = *(const half8*)&Bs[(gK >> 1) * 2048 + row * 16 + (gK & 1) * 8];
            }
#pragma unroll
            for (int mi = 0; mi < 2; mi++)
#pragma unroll
                for (int ni = 0; ni < 4; ni++)
                    acc[mi][ni] = __builtin_amdgcn_mfma_f32_16x16x32_f16(
                        af[mi], bfr[ni], acc[mi][ni], 0, 0, 0);
        }
        __syncthreads();
    }

#pragma unroll
    for (int mi = 0; mi < 2; mi++)
#pragma unroll
        for (int ni = 0; ni < 4; ni++) {
            f32x4 a = acc[mi][ni];
            float vals[4] = {a.x, a.y, a.z, a.w};
#pragma unroll
            for (int r = 0; r < 4; r++) {
                int c = cB + wm * 32 + mi * 16 + q * 4 + r;
                int n = nB + wn * 64 + ni * 16 + ln;
                size_t o = ((size_t)b * C1 + c) * NN + n;
                out[o] = x[o] + vals[r];
            }
        }
}

// ---------------------------------------------------------------------------
extern "C" void kernel_launch(void* const* d_in, const int* in_sizes, int n_in,
                              void* d_out, int out_size, void* d_ws, size_t ws_size,
                              hipStream_t stream)
{
    const float* x  = (const float*)d_in[0];
    const float* w1 = (const float*)d_in[1];
    const float* g1 = (const float*)d_in[2];
    const float* b1 = (const float*)d_in[3];
    const float* m1 = (const float*)d_in[4];
    const float* v1 = (const float*)d_in[5];
    const float* w2 = (const float*)d_in[6];
    const float* g2 = (const float*)d_in[7];
    const float* b2 = (const float*)d_in[8];
    const float* m2 = (const float*)d_in[9];
    const float* v2 = (const float*)d_in[10];
    float* out = (float*)d_out;

    // workspace (86.6 MB total):
    //  xh [17,301,504 us] -- dead after conv1, REUSED as y_hi [16,777,216 us]
    //  y1h [8,650,752 us] -- dead after conv2, REUSED as sc0+sc1 (fp32
    //    split-K partials) + attn16
    unsigned short* xh   = (unsigned short*)d_ws;
    unsigned short* y1h  = xh  + (size_t)17301504;
    unsigned short* wt1  = y1h + (size_t)8650752;
    unsigned short* wt2  = wt1 + (size_t)294912;
    unsigned short* yhiT = wt2 + (size_t)294912;
    unsigned short* yhi  = xh;                         // alias (xh dead)
    float*          sc   = (float*)y1h;                // alias (y1h dead)
    unsigned short* attn16 = (unsigned short*)(sc + 2097152);

    // pre-pass
    nchw_to_nhwc_f16<<<dim3(C1 / 64, 66, BB), 256, 0, stream>>>(x, xh, C1);
    pack_w_kernel<<<(9 * CHD * C1 + 255) / 256, 256, 0, stream>>>(w1, wt1, CHD, C1);
    pack_w_kernel<<<(9 * C1 * CHD + 255) / 256, 256, 0, stream>>>(w2, wt2, C1, CHD);
    zero_y1h_pads<<<256, 256, 0, stream>>>(y1h);

    // conv1: 256 -> 128, chunked half-split fp16 NHWC out (padded rows)
    conv_mfma_kernel<<<dim3(CHD / 64, 8, BB), 512, 0, stream>>>(
        xh, wt1, g1, b1, m1, v1, y1h, nullptr, nullptr, C1, CHD);
    // conv2: 128 -> 256, y_hi NCHW + yhiT chunked NHWC (overwrites xh region)
    conv_mfma_kernel<<<dim3(C1 / 64, 8, BB), 512, 0, stream>>>(
        y1h, wt2, g2, b2, m2, v2, nullptr, yhi, yhiT, CHD, C1);

    // attention: split-K symmetric fp16 MFMA scores -> softmax(sum halves)
    // -> fp16 MFMA PV + residual
    scores_mfma_kernel<<<dim3(10, 2, BB), 256, 0, stream>>>(yhi, sc);
    softmax_kernel<<<dim3(BB * C1), 64, 0, stream>>>(sc, attn16);
    out_mfma_kernel<<<dim3(NN / 128, 4, BB), 256, 0, stream>>>(attn16, yhiT, x, out);
}

// Round 8
// 302.479 us; speedup vs baseline: 1.0428x; 1.0428x over previous
//
#include <hip/hip_runtime.h>
#include <math.h>

// Problem constants
#define BB 16
#define C1 256     // in/out channels of the block
#define CHD 128    // hidden channels
#define NN 4096    // H*W
#define INV_T (1.0f/16.0f)   // TEMPERATURE = sqrt(256) = 16

typedef _Float16 half8 __attribute__((ext_vector_type(8)));
typedef __attribute__((ext_vector_type(4))) float f32x4;
typedef __attribute__((ext_vector_type(16))) float f32x16;

__device__ inline unsigned short f2h(float f) {
    _Float16 h = (_Float16)f;            // RN conversion
    return __builtin_bit_cast(unsigned short, h);
}

// async global->LDS, 16B per lane; LDS dest = wave-uniform base + lane*16
#define GLDS(g, l) __builtin_amdgcn_global_load_lds(                              \
    (const __attribute__((address_space(1))) unsigned int*)(g),                   \
    (__attribute__((address_space(3))) unsigned int*)(l), 16, 0, 0)

// XCD-chunked bijective blockIdx swizzle (T1). Requires nwg % 8 == 0.
__device__ inline void xcd_remap(int& bx, int& by, int& bz) {
    int gx = gridDim.x, gy = gridDim.y;
    int lin = blockIdx.x + gx * (blockIdx.y + gy * blockIdx.z);
    int cpx = (gx * gy * (int)gridDim.z) >> 3;
    lin = (lin & 7) * cpx + (lin >> 3);
    bx = lin % gx; int t = lin / gx; by = t % gy; bz = t / gy;
}

// ---------------------------------------------------------------------------
// NCHW fp32 -> CHUNKED half-split padded NHWC fp16:
// xh[b][ck=c/16][hp][cihalf(2)][w(64)][8ci], hp in [0,66), rows 0 & 65 zero.
// ---------------------------------------------------------------------------
__global__ __launch_bounds__(256) void nchw_to_nhwc_f16(
    const float* __restrict__ x, unsigned short* __restrict__ xh, int C)
{
    const int c0 = blockIdx.x * 64;
    const int hp = blockIdx.y;
    const int b  = blockIdx.z;
    const int nCk = C >> 4;

    if (hp == 0 || hp == 65) {
        for (int idx = threadIdx.x; idx < 1024; idx += 256) {
            int w = idx >> 4, cq = (idx & 15) * 4;
            int ck = (c0 >> 4) + (cq >> 4), half = (cq >> 3) & 1, rem = cq & 7;
            ushort4 z; z.x = z.y = z.z = z.w = 0;
            *(ushort4*)&xh[(((((size_t)b * nCk + ck) * 66 + hp) * 2 + half) * 64 + w) * 8
                           + rem] = z;
        }
        return;
    }
    const int h = hp - 1;
    __shared__ float ts[64][65];
    for (int idx = threadIdx.x; idx < 4096; idx += 256) {
        int cl = idx >> 6, w = idx & 63;
        ts[cl][w] = x[(((size_t)b * C + c0 + cl) * 64 + h) * 64 + w];
    }
    __syncthreads();
    for (int idx = threadIdx.x; idx < 1024; idx += 256) {
        int w = idx >> 4, cq = (idx & 15) * 4;
        int ck = (c0 >> 4) + (cq >> 4), half = (cq >> 3) & 1, rem = cq & 7;
        ushort4 o;
        o.x = f2h(ts[cq + 0][w]); o.y = f2h(ts[cq + 1][w]);
        o.z = f2h(ts[cq + 2][w]); o.w = f2h(ts[cq + 3][w]);
        *(ushort4*)&xh[(((((size_t)b * nCk + ck) * 66 + hp) * 2 + half) * 64 + w) * 8
                       + rem] = o;
    }
}

// ---------------------------------------------------------------------------
// Pack conv weights [Cout][Cin][3][3] fp32 -> [ck][kk][cihalf][Cout][8ci] fp16
// ---------------------------------------------------------------------------
__global__ __launch_bounds__(256) void pack_w_kernel(
    const float* __restrict__ w, unsigned short* __restrict__ wT, int Cout, int Cin)
{
    int idx = blockIdx.x * 256 + threadIdx.x;
    int total = Cout * Cin * 9;
    if (idx >= total) return;
    int ci = idx % Cin; int t = idx / Cin; int co = t % Cout; int kk = t / Cout;
    int ck = ci >> 4, half = (ci >> 3) & 1, rem = ci & 7;
    wT[((((size_t)ck * 9 + kk) * 2 + half) * Cout + co) * 8 + rem] =
        f2h(w[((size_t)co * Cin + ci) * 9 + kk]);
}

// ---------------------------------------------------------------------------
// Zero the pad rows (0 and 65) of chunked y1h [B][8ck][66][2][64][8]
// ---------------------------------------------------------------------------
__global__ __launch_bounds__(256) void zero_y1h_pads(unsigned short* __restrict__ y1h)
{
    int idx = blockIdx.x * 256 + threadIdx.x;   // 65536 ushort4 stores
    int b   = idx >> 12;
    int ck  = (idx >> 9) & 7;
    int row = ((idx >> 8) & 1) ? 65 : 0;
    int inner = (idx & 255) * 4;                 // 0..1020 step 4
    ushort4 z; z.x = z.y = z.z = z.w = 0;
    *(ushort4*)&y1h[(((size_t)b * 8 + ck) * 66 + row) * 1024 + inner] = z;
}

// ---------------------------------------------------------------------------
// Implicit-GEMM conv3x3 + BN + SiLU via fp16 MFMA (fp32 accumulate).
// Template<NW, ROWS>: NW waves (NW*64 threads), wave w -> output row h0+w
// as a 2x2 tile of mfma_f32_32x32x16_f16. ci chunked by 16, weights AND
// activations in double-buffered half-split LDS (R5 structure: the direct
// global A-load of R6 regressed -- 1-kk-ahead prefetch can't cover ~200cy
// L2 latency; LDS round-trip amortizes it behind the chunk barrier).
// conv1 uses <4,4>: grid (2,16,16)=512 blocks -> 2 blocks/CU (was grid-
// limited to 1 at <8,8>), same 8 waves/CU but INDEPENDENT barriers ->
// cross-block overlap of the vmcnt(0)+barrier drain (conv1 was latency-
// bound at 46% LDS-pipe use; conv2 at 16 waves/CU is pipe-saturated and
// stays <8,8>).
// conv1: outNHWC != nullptr -> chunked half-split NHWC y1h.
// conv2: yhi NCHW fp16 + yhiT chunked [b][ck][n][16d].
// ---------------------------------------------------------------------------
template<int NW, int ROWS>
__global__ __launch_bounds__(NW * 64, 4) void conv_mfma_kernel(
    const unsigned short* __restrict__ xh, const unsigned short* __restrict__ wT,
    const float* __restrict__ gamma, const float* __restrict__ beta,
    const float* __restrict__ mean, const float* __restrict__ var,
    unsigned short* __restrict__ outNHWC,
    unsigned short* __restrict__ yhi, unsigned short* __restrict__ yhiT,
    int Cin, int Cout)
{
    constexpr int XR    = ROWS + 2;            // staged rows incl. halo
    constexpr int XS_SZ = XR * 2 * 66 * 8;     // shorts per xs buffer
    constexpr int WS_SZ = 9 * 2 * 64 * 8;      // shorts per ws buffer (9216)

    int bx, by, bz;
    xcd_remap(bx, by, bz);
    const int tid  = threadIdx.x;
    const int wid  = tid >> 6;          // 0..NW-1, wave -> output row h0+wid
    const int lane = tid & 63;
    const int l31  = lane & 31;
    const int hi   = lane >> 5;
    const int coBase = bx * 64;
    const int h0     = by * ROWS;
    const int b      = bz;
    const int nCk    = Cin >> 4;

    // xs[2][XS_SZ]: [row][cihalf][col 0..65][8ci]; ws[2][WS_SZ]: [kk][half][co][8ci]
    // epilogue reuses smem[0 .. ROWS*4096) as os[ROWS][64 w][64 co] (swizzled)
    __shared__ __align__(16) unsigned short smem[2 * XS_SZ + 2 * WS_SZ];
    __shared__ float bnsc[64], bnsh[64];

    if (tid < 64) {
        int co = coBase + tid;
        float sc = gamma[co] * rsqrtf(var[co] + 1e-5f);
        bnsc[tid] = sc;
        bnsh[tid] = beta[co] - mean[co] * sc;
    }
    if (tid < 8 * XR) {   // zero halo cols 0/65: 2 buf x XR row x 2 half x 2 col
        int buf  = tid & 1;
        int col  = ((tid >> 1) & 1) ? 65 : 0;
        int half = (tid >> 2) & 1;
        int r    = tid >> 3;               // 0..XR-1
        ushort4 z; z.x = z.y = z.z = z.w = 0;
        *(ushort4*)&smem[buf * XS_SZ + ((r * 2 + half) * 66 + col) * 8] = z;
        *(ushort4*)&smem[buf * XS_SZ + ((r * 2 + half) * 66 + col) * 8 + 4] = z;
    }

    // stage one 16-ci chunk: 18 ws issues + 2*XR xs issues, all 1KB contiguous
    auto stage = [&](int sel, int ck) {
        unsigned short* wsd = smem + 2 * XS_SZ + sel * WS_SZ;
        unsigned short* xsd = smem + sel * XS_SZ;
        for (int it = wid; it < 18 + 2 * XR; it += NW) {
            if (it < 18) {
                int kk = it >> 1, half = it & 1;
                const unsigned short* g =
                    wT + ((((size_t)ck * 9 + kk) * 2 + half) * Cout + coBase) * 8 + lane * 8;
                GLDS(g, wsd + (kk * 2 + half) * 512);
            } else {
                int j = it - 18;                 // 0..2*XR-1
                int r = j >> 1, half = j & 1;
                const unsigned short* g =
                    xh + ((((size_t)b * nCk + ck) * 66 + h0 + r) * 2 + half) * 512 + lane * 8;
                GLDS(g, xsd + ((r * 2 + half) * 66 + 1) * 8);
            }
        }
    };

    stage(0, 0);
    __syncthreads();

    f32x16 acc[2][2] = {};

    int sel = 0;
    for (int ck = 0; ck < nCk; ck++) {
        if (ck + 1 < nCk) stage(sel ^ 1, ck + 1);   // prefetch next chunk

        const unsigned short* wsb = smem + 2 * XS_SZ + sel * WS_SZ;
        const unsigned short* xsb = smem + sel * XS_SZ;
        __builtin_amdgcn_s_setprio(1);
#pragma unroll
        for (int kk = 0; kk < 9; kk++) {
            const int kh = kk / 3, kw = kk % 3;
            half8 a0 = *(const half8*)&wsb[((kk * 2 + hi) * 64 +      l31) * 8];
            half8 a1 = *(const half8*)&wsb[((kk * 2 + hi) * 64 + 32 + l31) * 8];
            const unsigned short* xr =
                &xsb[(((wid + kh) * 2 + hi) * 66 + l31 + kw) * 8];
            half8 b0 = *(const half8*)xr;
            half8 b1 = *(const half8*)&xr[32 * 8];
            acc[0][0] = __builtin_amdgcn_mfma_f32_32x32x16_f16(a0, b0, acc[0][0], 0, 0, 0);
            acc[0][1] = __builtin_amdgcn_mfma_f32_32x32x16_f16(a0, b1, acc[0][1], 0, 0, 0);
            acc[1][0] = __builtin_amdgcn_mfma_f32_32x32x16_f16(a1, b0, acc[1][0], 0, 0, 0);
            acc[1][1] = __builtin_amdgcn_mfma_f32_32x32x16_f16(a1, b1, acc[1][1], 0, 0, 0);
        }
        __builtin_amdgcn_s_setprio(0);
        __syncthreads();   // next buffer staged + this buffer free to overwrite
        sel ^= 1;
    }

    // --------------------------------------------------------------
    // Epilogue. D layout (32x32): col=lane&31 -> w,
    // row = (reg&3) + 8*(reg>>2) + 4*hi -> co.
    // Stage BN+SiLU fp16 results into os[row][w][co] with XOR swizzle
    // ((w+row)&7)<<3 on the co-offset, then dense 1KB chunked writes.
    // --------------------------------------------------------------
    const int orow = h0 + wid;
    const bool isConv1 = (outNHWC != nullptr);

    __syncthreads();   // all K-loop LDS reads done before overwrite

#pragma unroll
    for (int mi = 0; mi < 2; mi++)
#pragma unroll
        for (int ni = 0; ni < 2; ni++) {
            f32x16 a = acc[mi][ni];
            int w = ni * 32 + l31;
            int swz = ((l31 + wid) & 7) << 3;
#pragma unroll
            for (int rq = 0; rq < 4; rq++) {
                int c0 = mi * 32 + rq * 8 + hi * 4;   // local co base
                ushort4 o; unsigned short* op = (unsigned short*)&o;
#pragma unroll
                for (int r = 0; r < 4; r++) {
                    float t = a[rq * 4 + r] * bnsc[c0 + r] + bnsh[c0 + r];
                    float s = t / (1.f + __expf(-t));
                    op[r] = f2h(s);
                    if (!isConv1)
                        yhi[(((size_t)b * Cout + coBase + c0 + r) * 64 + orow) * 64 + w] = op[r];
                }
                *(ushort4*)&smem[wid * 4096 + w * 64 + (c0 ^ swz)] = o;
            }
        }
    __syncthreads();

    // dense write-out: ROWS*512 16B units = [ck(4)][row(ROWS)][w(64)][s(2)];
    // unit g = j*(NW*64) + tid -> each instruction writes 1KB contiguous.
    constexpr int RSH = (ROWS == 8) ? 3 : 2;   // log2(ROWS)
    const int ckB = bx * 4;   // output chunk base
    const int nCkOut = Cout >> 4;
#pragma unroll
    for (int j = 0; j < 8; j++) {
        int g   = j * (NW * 64) + tid;
        int s   = g & 1;
        int w   = (g >> 1) & 63;
        int row = (g >> 7) & (ROWS - 1);
        int ck  = g >> (7 + RSH);
        uint4 v = *(const uint4*)&smem[row * 4096 + w * 64 +
                     (((ck * 2 + s) * 8) ^ (((w + row) & 7) << 3))];
        if (isConv1) {
            // y1h [b][ck][hp][cihalf=s][w][8]
            *(uint4*)&outNHWC[((((((size_t)b * nCkOut + ckB + ck) * 66 + h0 + row + 1) * 2 + s)
                               * 64 + w) * 8)] = v;
        } else {
            // yhiT [b][ck][n][16d] (byte-identical to [n][half][8])
            *(uint4*)&yhiT[(((size_t)b * nCkOut + ckB + ck) * 4096 + (size_t)(h0 + row) * 64 + w) * 16
                           + s * 8] = v;
        }
    }
}

// ---------------------------------------------------------------------------
// scores = (y . y^T)/16, fp16 MFMA, SYMMETRIC: only upper-triangle 64x64 tile
// pairs computed (10 of 16); each writes its tile and the transpose.
// SPLIT-K x2: blockIdx.y = kh selects n-half; partials summed in softmax.
// grid: (10, 2, 16)
// ---------------------------------------------------------------------------
__global__ __launch_bounds__(256) void scores_mfma_kernel(
    const unsigned short* __restrict__ yhi, float* __restrict__ scores)
{
    static const int TI[10] = {0,0,0,0,1,1,1,2,2,3};
    static const int TJ[10] = {0,1,2,3,1,2,3,2,3,3};
    int bx, by, bz;
    xcd_remap(bx, by, bz);
    const int b  = bz;
    const int kh = by;
    const int ti = TI[bx], tj = TJ[bx];
    const int cB = ti * 64;
    const int dB = tj * 64;
    const int tid  = threadIdx.x;
    const int wid  = tid >> 6;
    const int lane = tid & 63;
    const int ln   = lane & 15;
    const int q    = lane >> 4;
    const int wm   = wid >> 1, wn = wid & 1;

    float* scp = scores + (size_t)kh * 1048576;   // partial buffer for this half

    __shared__ unsigned short As[64 * 128];  // 16 KB, rows cB..cB+63, swizzled
    __shared__ unsigned short Bs[64 * 128];  // 16 KB, rows dB..dB+63, swizzled

    const int rl = lane >> 4;
    const int gl = lane & 15;

    f32x4 acc[2][2] = {};

    for (int ck = kh * 16; ck < kh * 16 + 16; ck++) {
        const int n0 = ck * 128;
        for (int it = wid; it < 32; it += 4) {
            const int tile = it >> 4;
            const int j = it & 15;
            const int r = j * 4 + rl;
            const int gq = gl ^ (r & 7);
            const int rowAbs = (tile ? dB : cB) + r;
            const unsigned short* g =
                yhi + ((size_t)b * 256 + rowAbs) * 4096 + n0 + gq * 8;
            GLDS(g, (tile ? Bs : As) + j * 512);
        }
        __syncthreads();

#pragma unroll
        for (int kwin = 0; kwin < 4; kwin++) {
            half8 ah[2], bh[2];
#pragma unroll
            for (int mi = 0; mi < 2; mi++) {
                int row = wm * 32 + mi * 16 + ln;
                ah[mi] = *(const half8*)&As[row * 128 + ((kwin * 4 + q) ^ (ln & 7)) * 8];
            }
#pragma unroll
            for (int ni = 0; ni < 2; ni++) {
                int row = wn * 32 + ni * 16 + ln;
                bh[ni] = *(const half8*)&Bs[row * 128 + ((kwin * 4 + q) ^ (ln & 7)) * 8];
            }
#pragma unroll
            for (int mi = 0; mi < 2; mi++)
#pragma unroll
                for (int ni = 0; ni < 2; ni++)
                    acc[mi][ni] = __builtin_amdgcn_mfma_f32_16x16x32_f16(
                        ah[mi], bh[ni], acc[mi][ni], 0, 0, 0);
        }
        __syncthreads();
    }

#pragma unroll
    for (int mi = 0; mi < 2; mi++)
#pragma unroll
        for (int ni = 0; ni < 2; ni++) {
            f32x4 a = acc[mi][ni];
            float vals[4];
            vals[0] = a.x * INV_T; vals[1] = a.y * INV_T;
            vals[2] = a.z * INV_T; vals[3] = a.w * INV_T;
            int c0 = cB + wm * 32 + mi * 16 + q * 4;
            int d  = dB + wn * 32 + ni * 16 + ln;
#pragma unroll
            for (int r = 0; r < 4; r++)
                scp[((size_t)b * C1 + c0 + r) * C1 + d] = vals[r];
            if (ti != tj) {   // mirror tile
                float4 tv = {vals[0], vals[1], vals[2], vals[3]};
                *(float4*)&scp[((size_t)b * C1 + d) * C1 + c0] = tv;
            }
        }
}

// ---------------------------------------------------------------------------
// Row softmax over 256 entries; sums the two split-K partial fp32 buffers,
// writes fp16 attn.
// ---------------------------------------------------------------------------
__global__ __launch_bounds__(64) void softmax_kernel(
    const float* __restrict__ scores, unsigned short* __restrict__ attn16)
{
    const int row = blockIdx.x;
    const float* p = scores + (size_t)row * C1;
    const int lane = threadIdx.x;

    float4 v0 = ((const float4*)p)[lane];
    float4 v1 = ((const float4*)(p + 1048576))[lane];
    float4 v;
    v.x = v0.x + v1.x; v.y = v0.y + v1.y;
    v.z = v0.z + v1.z; v.w = v0.w + v1.w;
    float m = fmaxf(fmaxf(v.x, v.y), fmaxf(v.z, v.w));
#pragma unroll
    for (int off = 32; off >= 1; off >>= 1)
        m = fmaxf(m, __shfl_xor(m, off, 64));

    float4 e;
    e.x = expf(v.x - m); e.y = expf(v.y - m);
    e.z = expf(v.z - m); e.w = expf(v.w - m);
    float s = e.x + e.y + e.z + e.w;
#pragma unroll
    for (int off = 32; off >= 1; off >>= 1)
        s += __shfl_xor(s, off, 64);
    float inv = 1.f / s;
    ushort4 o;
    o.x = f2h(e.x * inv); o.y = f2h(e.y * inv);
    o.z = f2h(e.z * inv); o.w = f2h(e.w * inv);
    *(ushort4*)&attn16[(size_t)row * C1 + lane * 4] = o;
}

// ---------------------------------------------------------------------------
// out[b][c][n] = x[b][c][n] + sum_d attn[c][d] * y[d][n]  via fp16 MFMA.
// A = attn16 [b][c][d] (k=d contiguous); B = yhiT CHUNKED [b][d/16][n][16d].
// Block tile 64c x 128n, 4 waves of 32x64. K-chunks of 64 (4 chunks).
// grid: (32, 4, 16)
// ---------------------------------------------------------------------------
__global__ __launch_bounds__(256) void out_mfma_kernel(
    const unsigned short* __restrict__ attn16, const unsigned short* __restrict__ yhiT,
    const float* __restrict__ x, float* __restrict__ out)
{
    int bx, by, bz;
    xcd_remap(bx, by, bz);
    const int b  = bz;
    const int cB = by * 64;
    const int nB = bx * 128;
    const int tid  = threadIdx.x;
    const int wid  = tid >> 6;
    const int lane = tid & 63;
    const int ln   = lane & 15;
    const int q    = lane >> 4;
    const int wm   = wid >> 1, wn = wid & 1;

    __shared__ unsigned short As[64 * 64];    //  8 KB, XOR-swizzled
    __shared__ unsigned short Bs[4 * 128 * 16];   // 16 KB: [u(4 d-sub)][128 n][16d]

    const int r8 = lane >> 3;
    const int gq = (lane & 7) ^ r8;

    f32x4 acc[2][4] = {};

    for (int ck = 0; ck < 4; ck++) {
        const int d0 = ck * 64;
        for (int it = wid; it < 24; it += 4) {
            if (it < 8) {
                const unsigned short* g =
                    attn16 + ((size_t)b * 256 + cB + it * 8 + r8) * 256 + d0 + gq * 8;
                GLDS(g, As + it * 512);
            } else {
                int j = it - 8;            // 0..15
                int u = j >> 2, part = j & 3;
                const unsigned short* g =
                    yhiT + (((size_t)b * 16 + ck * 4 + u) * 4096 + nB + part * 32) * 16 + lane * 8;
                GLDS(g, Bs + (u * 128 + part * 32) * 16);
            }
        }
        __syncthreads();

#pragma unroll
        for (int kwin = 0; kwin < 2; kwin++) {
            const int cc = (((kwin * 4 + q) ^ (ln & 7))) * 8;
            const int gK = kwin * 4 + q;
            half8 af[2], bfr[4];
#pragma unroll
            for (int mi = 0; mi < 2; mi++)
                af[mi] = *(const half8*)&As[(wm * 32 + mi * 16 + ln) * 64 + cc];
#pragma unroll
            for (int ni = 0; ni < 4; ni++) {
                int row = wn * 64 + ni * 16 + ln;
                bfr[ni] = *(const half8*)&Bs[(gK >> 1) * 2048 + row * 16 + (gK & 1) * 8];
            }
#pragma unroll
            for (int mi = 0; mi < 2; mi++)
#pragma unroll
                for (int ni = 0; ni < 4; ni++)
                    acc[mi][ni] = __builtin_amdgcn_mfma_f32_16x16x32_f16(
                        af[mi], bfr[ni], acc[mi][ni], 0, 0, 0);
        }
        __syncthreads();
    }

#pragma unroll
    for (int mi = 0; mi < 2; mi++)
#pragma unroll
        for (int ni = 0; ni < 4; ni++) {
            f32x4 a = acc[mi][ni];
            float vals[4] = {a.x, a.y, a.z, a.w};
#pragma unroll
            for (int r = 0; r < 4; r++) {
                int c = cB + wm * 32 + mi * 16 + q * 4 + r;
                int n = nB + wn * 64 + ni * 16 + ln;
                size_t o = ((size_t)b * C1 + c) * NN + n;
                out[o] = x[o] + vals[r];
            }
        }
}

// ---------------------------------------------------------------------------
extern "C" void kernel_launch(void* const* d_in, const int* in_sizes, int n_in,
                              void* d_out, int out_size, void* d_ws, size_t ws_size,
                              hipStream_t stream)
{
    const float* x  = (const float*)d_in[0];
    const float* w1 = (const float*)d_in[1];
    const float* g1 = (const float*)d_in[2];
    const float* b1 = (const float*)d_in[3];
    const float* m1 = (const float*)d_in[4];
    const float* v1 = (const float*)d_in[5];
    const float* w2 = (const float*)d_in[6];
    const float* g2 = (const float*)d_in[7];
    const float* b2 = (const float*)d_in[8];
    const float* m2 = (const float*)d_in[9];
    const float* v2 = (const float*)d_in[10];
    float* out = (float*)d_out;

    // workspace (86.6 MB total):
    //  xh [17,301,504 us] -- dead after conv1, REUSED as y_hi [16,777,216 us]
    //  y1h [8,650,752 us] -- dead after conv2, REUSED as sc0+sc1 (fp32
    //    split-K partials) + attn16
    unsigned short* xh   = (unsigned short*)d_ws;
    unsigned short* y1h  = xh  + (size_t)17301504;
    unsigned short* wt1  = y1h + (size_t)8650752;
    unsigned short* wt2  = wt1 + (size_t)294912;
    unsigned short* yhiT = wt2 + (size_t)294912;
    unsigned short* yhi  = xh;                         // alias (xh dead)
    float*          sc   = (float*)y1h;                // alias (y1h dead)
    unsigned short* attn16 = (unsigned short*)(sc + 2097152);

    // pre-pass
    nchw_to_nhwc_f16<<<dim3(C1 / 64, 66, BB), 256, 0, stream>>>(x, xh, C1);
    pack_w_kernel<<<(9 * CHD * C1 + 255) / 256, 256, 0, stream>>>(w1, wt1, CHD, C1);
    pack_w_kernel<<<(9 * C1 * CHD + 255) / 256, 256, 0, stream>>>(w2, wt2, C1, CHD);
    zero_y1h_pads<<<256, 256, 0, stream>>>(y1h);

    // conv1: 256 -> 128, 4-row/4-wave blocks (512 blocks -> 2 blocks/CU,
    // independent barriers hide the chunk drain; conv1 was latency-bound)
    conv_mfma_kernel<4, 4><<<dim3(CHD / 64, 16, BB), 256, 0, stream>>>(
        xh, wt1, g1, b1, m1, v1, y1h, nullptr, nullptr, C1, CHD);
    // conv2: 128 -> 256, 8-row/8-wave blocks (LDS-pipe-saturated at 16
    // waves/CU -- keep), y_hi NCHW + yhiT chunked NHWC
    conv_mfma_kernel<8, 8><<<dim3(C1 / 64, 8, BB), 512, 0, stream>>>(
        y1h, wt2, g2, b2, m2, v2, nullptr, yhi, yhiT, CHD, C1);

    // attention: split-K symmetric fp16 MFMA scores -> softmax(sum halves)
    // -> fp16 MFMA PV + residual
    scores_mfma_kernel<<<dim3(10, 2, BB), 256, 0, stream>>>(yhi, sc);
    softmax_kernel<<<dim3(BB * C1), 64, 0, stream>>>(sc, attn16);
    out_mfma_kernel<<<dim3(NN / 128, 4, BB), 256, 0, stream>>>(attn16, yhiT, x, out);
}

// Round 9
// 278.911 us; speedup vs baseline: 1.1309x; 1.0845x over previous
//
#include <hip/hip_runtime.h>
#include <math.h>

// Problem constants
#define BB 16
#define C1 256     // in/out channels of the block
#define CHD 128    // hidden channels
#define NN 4096    // H*W
#define INV_T (1.0f/16.0f)   // TEMPERATURE = sqrt(256) = 16

typedef _Float16 half8 __attribute__((ext_vector_type(8)));
typedef __attribute__((ext_vector_type(4))) float f32x4;
typedef __attribute__((ext_vector_type(16))) float f32x16;

__device__ inline unsigned short f2h(float f) {
    _Float16 h = (_Float16)f;            // RN conversion
    return __builtin_bit_cast(unsigned short, h);
}

// async global->LDS, 16B per lane; LDS dest = wave-uniform base + lane*16
#define GLDS(g, l) __builtin_amdgcn_global_load_lds(                              \
    (const __attribute__((address_space(1))) unsigned int*)(g),                   \
    (__attribute__((address_space(3))) unsigned int*)(l), 16, 0, 0)

// XCD-chunked bijective blockIdx swizzle (T1). Requires nwg % 8 == 0.
__device__ inline void xcd_remap(int& bx, int& by, int& bz) {
    int gx = gridDim.x, gy = gridDim.y;
    int lin = blockIdx.x + gx * (blockIdx.y + gy * blockIdx.z);
    int cpx = (gx * gy * (int)gridDim.z) >> 3;
    lin = (lin & 7) * cpx + (lin >> 3);
    bx = lin % gx; int t = lin / gx; by = t % gy; bz = t / gy;
}

// ---------------------------------------------------------------------------
// NCHW fp32 -> CHUNKED half-split padded NHWC fp16:
// xh[b][ck=c/16][hp][cihalf(2)][w(64)][8ci], hp in [0,66), rows 0 & 65 zero.
// float4 global reads (4x fewer load issues).
// ---------------------------------------------------------------------------
__global__ __launch_bounds__(256) void nchw_to_nhwc_f16(
    const float* __restrict__ x, unsigned short* __restrict__ xh, int C)
{
    const int c0 = blockIdx.x * 64;
    const int hp = blockIdx.y;
    const int b  = blockIdx.z;
    const int nCk = C >> 4;

    if (hp == 0 || hp == 65) {
        for (int idx = threadIdx.x; idx < 1024; idx += 256) {
            int w = idx >> 4, cq = (idx & 15) * 4;
            int ck = (c0 >> 4) + (cq >> 4), half = (cq >> 3) & 1, rem = cq & 7;
            ushort4 z; z.x = z.y = z.z = z.w = 0;
            *(ushort4*)&xh[(((((size_t)b * nCk + ck) * 66 + hp) * 2 + half) * 64 + w) * 8
                           + rem] = z;
        }
        return;
    }
    const int h = hp - 1;
    __shared__ float ts[64][65];
    for (int idx = threadIdx.x; idx < 1024; idx += 256) {
        int cl = idx >> 4, w4 = (idx & 15) * 4;
        float4 v = *(const float4*)&x[(((size_t)b * C + c0 + cl) * 64 + h) * 64 + w4];
        ts[cl][w4 + 0] = v.x; ts[cl][w4 + 1] = v.y;
        ts[cl][w4 + 2] = v.z; ts[cl][w4 + 3] = v.w;
    }
    __syncthreads();
    for (int idx = threadIdx.x; idx < 1024; idx += 256) {
        int w = idx >> 4, cq = (idx & 15) * 4;
        int ck = (c0 >> 4) + (cq >> 4), half = (cq >> 3) & 1, rem = cq & 7;
        ushort4 o;
        o.x = f2h(ts[cq + 0][w]); o.y = f2h(ts[cq + 1][w]);
        o.z = f2h(ts[cq + 2][w]); o.w = f2h(ts[cq + 3][w]);
        *(ushort4*)&xh[(((((size_t)b * nCk + ck) * 66 + hp) * 2 + half) * 64 + w) * 8
                       + rem] = o;
    }
}

// ---------------------------------------------------------------------------
// Fused prep: pack w1 -> wt1, pack w2 -> wt2 ([ck][kk][cihalf][Cout][8ci]),
// zero pad rows of y1h. One launch instead of three.
// grid: 2560 x 256
// ---------------------------------------------------------------------------
__global__ __launch_bounds__(256) void prep_kernel(
    const float* __restrict__ w1, const float* __restrict__ w2,
    unsigned short* __restrict__ wt1, unsigned short* __restrict__ wt2,
    unsigned short* __restrict__ y1h)
{
    const int P = 9 * CHD * C1;                 // 294912 (both packs equal)
    int idx = blockIdx.x * 256 + threadIdx.x;
    if (idx < P) {
        // pack w1: Cout=CHD, Cin=C1
        int ci = idx % C1; int t = idx / C1; int co = t % CHD; int kk = t / CHD;
        int ck = ci >> 4, half = (ci >> 3) & 1, rem = ci & 7;
        wt1[((((size_t)ck * 9 + kk) * 2 + half) * CHD + co) * 8 + rem] =
            f2h(w1[((size_t)co * C1 + ci) * 9 + kk]);
    } else if (idx < 2 * P) {
        // pack w2: Cout=C1, Cin=CHD
        idx -= P;
        int ci = idx % CHD; int t = idx / CHD; int co = t % C1; int kk = t / C1;
        int ck = ci >> 4, half = (ci >> 3) & 1, rem = ci & 7;
        wt2[((((size_t)ck * 9 + kk) * 2 + half) * C1 + co) * 8 + rem] =
            f2h(w2[((size_t)co * CHD + ci) * 9 + kk]);
    } else {
        // zero pad rows of y1h [B][8ck][66][1024]
        idx -= 2 * P;                           // 0..65535
        int b   = idx >> 12;
        int ck  = (idx >> 9) & 7;
        int row = ((idx >> 8) & 1) ? 65 : 0;
        int inner = (idx & 255) * 4;
        ushort4 z; z.x = z.y = z.z = z.w = 0;
        *(ushort4*)&y1h[(((size_t)b * 8 + ck) * 66 + row) * 1024 + inner] = z;
    }
}

// ---------------------------------------------------------------------------
// Implicit-GEMM conv3x3 + BN + SiLU via fp16 MFMA (fp32 accumulate).
// 512 threads = 8 waves; wave w -> output row h0+w as 2x2 tiles of
// mfma_f32_32x32x16_f16. ci chunked by 16, half-split double-buffered LDS
// (conflict-free), prefetch-before-compute, one barrier per chunk.
// Both convs use this shape (R8 A/B: per-CU totals are identical across
// wave shapes and time is identical -- the 2-barrier schedule is the floor).
// conv1: outNHWC != nullptr -> chunked half-split NHWC y1h.
// conv2: yhi NCHW fp16 + yhiT chunked [b][ck][n][16d].
// grid: (Cout/64, 8, B), block 512.
// ---------------------------------------------------------------------------
__global__ __launch_bounds__(512, 4) void conv_mfma_kernel(
    const unsigned short* __restrict__ xh, const unsigned short* __restrict__ wT,
    const float* __restrict__ gamma, const float* __restrict__ beta,
    const float* __restrict__ mean, const float* __restrict__ var,
    unsigned short* __restrict__ outNHWC,
    unsigned short* __restrict__ yhi, unsigned short* __restrict__ yhiT,
    int Cin, int Cout)
{
    int bx, by, bz;
    xcd_remap(bx, by, bz);
    const int tid  = threadIdx.x;
    const int wid  = tid >> 6;          // 0..7, wave -> output row h0+wid
    const int lane = tid & 63;
    const int l31  = lane & 31;
    const int hi   = lane >> 5;
    const int coBase = bx * 64;
    const int h0     = by * 8;
    const int b      = bz;
    const int nCk    = Cin >> 4;

    // xs[2][10560]: [row 0..9][cihalf][col 0..65][8ci]
    // ws[2][9216]:  [kk][cihalf][co 0..63][8ci]
    // epilogue reuses smem[0..32767] as os[8 row][64 w][64 co] (swizzled)
    __shared__ __align__(16) unsigned short smem[39552];   // 79104 B
    __shared__ float bnsc[64], bnsh[64];

    if (tid < 64) {
        int co = coBase + tid;
        float sc = gamma[co] * rsqrtf(var[co] + 1e-5f);
        bnsc[tid] = sc;
        bnsh[tid] = beta[co] - mean[co] * sc;
    }
    if (tid < 80) {   // zero halo cols 0 and 65: 2 buf x 10 row x 2 half x 2 col
        int buf  = tid & 1;
        int col  = ((tid >> 1) & 1) ? 65 : 0;
        int half = (tid >> 2) & 1;
        int r    = tid >> 3;               // 0..9
        ushort4 z; z.x = z.y = z.z = z.w = 0;
        *(ushort4*)&smem[buf * 10560 + ((r * 2 + half) * 66 + col) * 8] = z;
        *(ushort4*)&smem[buf * 10560 + ((r * 2 + half) * 66 + col) * 8 + 4] = z;
    }

    // stage one 16-ci chunk: 18 ws issues + 20 xs issues, all 1KB contiguous
    auto stage = [&](int sel, int ck) {
        unsigned short* wsd = smem + 21120 + sel * 9216;
        unsigned short* xsd = smem + sel * 10560;
        for (int it = wid; it < 38; it += 8) {
            if (it < 18) {
                int kk = it >> 1, half = it & 1;
                const unsigned short* g =
                    wT + ((((size_t)ck * 9 + kk) * 2 + half) * Cout + coBase) * 8 + lane * 8;
                GLDS(g, wsd + (kk * 2 + half) * 512);
            } else {
                int j = it - 18;                 // 0..19
                int r = j >> 1, half = j & 1;
                const unsigned short* g =
                    xh + ((((size_t)b * nCk + ck) * 66 + h0 + r) * 2 + half) * 512 + lane * 8;
                GLDS(g, xsd + ((r * 2 + half) * 66 + 1) * 8);
            }
        }
    };

    stage(0, 0);
    __syncthreads();

    f32x16 acc[2][2] = {};

    int sel = 0;
    for (int ck = 0; ck < nCk; ck++) {
        if (ck + 1 < nCk) stage(sel ^ 1, ck + 1);   // prefetch next chunk

        const unsigned short* wsb = smem + 21120 + sel * 9216;
        const unsigned short* xsb = smem + sel * 10560;
        __builtin_amdgcn_s_setprio(1);
#pragma unroll
        for (int kk = 0; kk < 9; kk++) {
            const int kh = kk / 3, kw = kk % 3;
            half8 a0 = *(const half8*)&wsb[((kk * 2 + hi) * 64 +      l31) * 8];
            half8 a1 = *(const half8*)&wsb[((kk * 2 + hi) * 64 + 32 + l31) * 8];
            const unsigned short* xr =
                &xsb[(((wid + kh) * 2 + hi) * 66 + l31 + kw) * 8];
            half8 b0 = *(const half8*)xr;
            half8 b1 = *(const half8*)&xr[32 * 8];
            acc[0][0] = __builtin_amdgcn_mfma_f32_32x32x16_f16(a0, b0, acc[0][0], 0, 0, 0);
            acc[0][1] = __builtin_amdgcn_mfma_f32_32x32x16_f16(a0, b1, acc[0][1], 0, 0, 0);
            acc[1][0] = __builtin_amdgcn_mfma_f32_32x32x16_f16(a1, b0, acc[1][0], 0, 0, 0);
            acc[1][1] = __builtin_amdgcn_mfma_f32_32x32x16_f16(a1, b1, acc[1][1], 0, 0, 0);
        }
        __builtin_amdgcn_s_setprio(0);
        __syncthreads();   // next buffer staged + this buffer free to overwrite
        sel ^= 1;
    }

    // --------------------------------------------------------------
    // Epilogue. D layout (32x32): col=lane&31 -> w,
    // row = (reg&3) + 8*(reg>>2) + 4*hi -> co.
    // Stage BN+SiLU fp16 results into os[row][w][co] with XOR swizzle
    // ((w+row)&7)<<3 on the co-offset, then dense 1KB chunked writes.
    // --------------------------------------------------------------
    const int orow = h0 + wid;
    const bool isConv1 = (outNHWC != nullptr);

    __syncthreads();   // all K-loop LDS reads done before overwrite

#pragma unroll
    for (int mi = 0; mi < 2; mi++)
#pragma unroll
        for (int ni = 0; ni < 2; ni++) {
            f32x16 a = acc[mi][ni];
            int w = ni * 32 + l31;
            int swz = ((l31 + wid) & 7) << 3;
#pragma unroll
            for (int rq = 0; rq < 4; rq++) {
                int c0 = mi * 32 + rq * 8 + hi * 4;   // local co base
                ushort4 o; unsigned short* op = (unsigned short*)&o;
#pragma unroll
                for (int r = 0; r < 4; r++) {
                    float t = a[rq * 4 + r] * bnsc[c0 + r] + bnsh[c0 + r];
                    float s = t / (1.f + __expf(-t));
                    op[r] = f2h(s);
                    if (!isConv1)
                        yhi[(((size_t)b * Cout + coBase + c0 + r) * 64 + orow) * 64 + w] = op[r];
                }
                *(ushort4*)&smem[wid * 4096 + w * 64 + (c0 ^ swz)] = o;
            }
        }
    __syncthreads();

    // dense write-out: 4096 16B units = [ck(4)][row(8)][w(64)][s(2)];
    // unit g = j*512 + tid -> each instruction writes 1KB contiguous.
    const int ckB = bx * 4;   // output chunk base
    const int nCkOut = Cout >> 4;
#pragma unroll
    for (int j = 0; j < 8; j++) {
        int g   = j * 512 + tid;
        int s   = g & 1;
        int w   = (g >> 1) & 63;
        int row = (g >> 7) & 7;
        int ck  = g >> 10;
        uint4 v = *(const uint4*)&smem[row * 4096 + w * 64 +
                     (((ck * 2 + s) * 8) ^ (((w + row) & 7) << 3))];
        if (isConv1) {
            // y1h [b][ck][hp][cihalf=s][w][8]
            *(uint4*)&outNHWC[((((((size_t)b * nCkOut + ckB + ck) * 66 + h0 + row + 1) * 2 + s)
                               * 64 + w) * 8)] = v;
        } else {
            // yhiT [b][ck][n][16d] (byte-identical to [n][half][8])
            *(uint4*)&yhiT[(((size_t)b * nCkOut + ckB + ck) * 4096 + (size_t)(h0 + row) * 64 + w) * 16
                           + s * 8] = v;
        }
    }
}

// ---------------------------------------------------------------------------
// scores = (y . y^T)/16, fp16 MFMA, SYMMETRIC: only upper-triangle 64x64 tile
// pairs computed (10 of 16); each writes its tile and the transpose.
// SPLIT-K x3: blockIdx.y = kh selects n-third (11/11/10 of 32 chunks);
// partials summed in softmax. 480 blocks -> ~1.9 blocks/CU (was 1.25),
// serial chunk chain 16 -> <=11.
// grid: (10, 3, 16)
// ---------------------------------------------------------------------------
__global__ __launch_bounds__(256) void scores_mfma_kernel(
    const unsigned short* __restrict__ yhi, float* __restrict__ scores)
{
    static const int TI[10] = {0,0,0,0,1,1,1,2,2,3};
    static const int TJ[10] = {0,1,2,3,1,2,3,2,3,3};
    int bx, by, bz;
    xcd_remap(bx, by, bz);
    const int b  = bz;
    const int kh = by;
    const int ti = TI[bx], tj = TJ[bx];
    const int cB = ti * 64;
    const int dB = tj * 64;
    const int tid  = threadIdx.x;
    const int wid  = tid >> 6;
    const int lane = tid & 63;
    const int ln   = lane & 15;
    const int q    = lane >> 4;
    const int wm   = wid >> 1, wn = wid & 1;

    float* scp = scores + (size_t)kh * 1048576;   // partial buffer for this third

    __shared__ unsigned short As[64 * 128];  // 16 KB, rows cB..cB+63, swizzled
    __shared__ unsigned short Bs[64 * 128];  // 16 KB, rows dB..dB+63, swizzled

    const int rl = lane >> 4;
    const int gl = lane & 15;

    f32x4 acc[2][2] = {};

    const int ckEnd = (kh == 2) ? 32 : kh * 11 + 11;
    for (int ck = kh * 11; ck < ckEnd; ck++) {
        const int n0 = ck * 128;
        for (int it = wid; it < 32; it += 4) {
            const int tile = it >> 4;
            const int j = it & 15;
            const int r = j * 4 + rl;
            const int gq = gl ^ (r & 7);
            const int rowAbs = (tile ? dB : cB) + r;
            const unsigned short* g =
                yhi + ((size_t)b * 256 + rowAbs) * 4096 + n0 + gq * 8;
            GLDS(g, (tile ? Bs : As) + j * 512);
        }
        __syncthreads();

#pragma unroll
        for (int kwin = 0; kwin < 4; kwin++) {
            half8 ah[2], bh[2];
#pragma unroll
            for (int mi = 0; mi < 2; mi++) {
                int row = wm * 32 + mi * 16 + ln;
                ah[mi] = *(const half8*)&As[row * 128 + ((kwin * 4 + q) ^ (ln & 7)) * 8];
            }
#pragma unroll
            for (int ni = 0; ni < 2; ni++) {
                int row = wn * 32 + ni * 16 + ln;
                bh[ni] = *(const half8*)&Bs[row * 128 + ((kwin * 4 + q) ^ (ln & 7)) * 8];
            }
#pragma unroll
            for (int mi = 0; mi < 2; mi++)
#pragma unroll
                for (int ni = 0; ni < 2; ni++)
                    acc[mi][ni] = __builtin_amdgcn_mfma_f32_16x16x32_f16(
                        ah[mi], bh[ni], acc[mi][ni], 0, 0, 0);
        }
        __syncthreads();
    }

#pragma unroll
    for (int mi = 0; mi < 2; mi++)
#pragma unroll
        for (int ni = 0; ni < 2; ni++) {
            f32x4 a = acc[mi][ni];
            float vals[4];
            vals[0] = a.x * INV_T; vals[1] = a.y * INV_T;
            vals[2] = a.z * INV_T; vals[3] = a.w * INV_T;
            int c0 = cB + wm * 32 + mi * 16 + q * 4;
            int d  = dB + wn * 32 + ni * 16 + ln;
#pragma unroll
            for (int r = 0; r < 4; r++)
                scp[((size_t)b * C1 + c0 + r) * C1 + d] = vals[r];
            if (ti != tj) {   // mirror tile
                float4 tv = {vals[0], vals[1], vals[2], vals[3]};
                *(float4*)&scp[((size_t)b * C1 + d) * C1 + c0] = tv;
            }
        }
}

// ---------------------------------------------------------------------------
// Row softmax over 256 entries; sums the three split-K partial fp32 buffers,
// writes fp16 attn.
// ---------------------------------------------------------------------------
__global__ __launch_bounds__(64) void softmax_kernel(
    const float* __restrict__ scores, unsigned short* __restrict__ attn16)
{
    const int row = blockIdx.x;
    const float* p = scores + (size_t)row * C1;
    const int lane = threadIdx.x;

    float4 v0 = ((const float4*)p)[lane];
    float4 v1 = ((const float4*)(p + 1048576))[lane];
    float4 v2 = ((const float4*)(p + 2097152))[lane];
    float4 v;
    v.x = v0.x + v1.x + v2.x; v.y = v0.y + v1.y + v2.y;
    v.z = v0.z + v1.z + v2.z; v.w = v0.w + v1.w + v2.w;
    float m = fmaxf(fmaxf(v.x, v.y), fmaxf(v.z, v.w));
#pragma unroll
    for (int off = 32; off >= 1; off >>= 1)
        m = fmaxf(m, __shfl_xor(m, off, 64));

    float4 e;
    e.x = expf(v.x - m); e.y = expf(v.y - m);
    e.z = expf(v.z - m); e.w = expf(v.w - m);
    float s = e.x + e.y + e.z + e.w;
#pragma unroll
    for (int off = 32; off >= 1; off >>= 1)
        s += __shfl_xor(s, off, 64);
    float inv = 1.f / s;
    ushort4 o;
    o.x = f2h(e.x * inv); o.y = f2h(e.y * inv);
    o.z = f2h(e.z * inv); o.w = f2h(e.w * inv);
    *(ushort4*)&attn16[(size_t)row * C1 + lane * 4] = o;
}

// ---------------------------------------------------------------------------
// out[b][c][n] = x[b][c][n] + sum_d attn[c][d] * y[d][n]  via fp16 MFMA.
// A = attn16 [b][c][d] (k=d contiguous); B = yhiT CHUNKED [b][d/16][n][16d].
// Block tile 64c x 128n, 4 waves of 32x64. K-chunks of 64 (4 chunks).
// NEW: float4 residual epilogue -- acc staged to a 64x132-padded fp32 LDS
// tile, then x-read + out-write as full float4 (was 32 scalar 4B ops per
// thread on the 134 MB x+out stream).
// grid: (32, 4, 16)
// ---------------------------------------------------------------------------
__global__ __launch_bounds__(256) void out_mfma_kernel(
    const unsigned short* __restrict__ attn16, const unsigned short* __restrict__ yhiT,
    const float* __restrict__ x, float* __restrict__ out)
{
    int bx, by, bz;
    xcd_remap(bx, by, bz);
    const int b  = bz;
    const int cB = by * 64;
    const int nB = bx * 128;
    const int tid  = threadIdx.x;
    const int wid  = tid >> 6;
    const int lane = tid & 63;
    const int ln   = lane & 15;
    const int q    = lane >> 4;
    const int wm   = wid >> 1, wn = wid & 1;

    // K-loop: As = smem[0..4096), Bs = smem[4096..12288) (shorts)
    // epilogue: os = (float*)smem, 64 x 132 padded fp32 tile (33792 B)
    __shared__ __align__(16) unsigned short smem[16896];
    unsigned short* As = smem;                 // 64*64
    unsigned short* Bs = smem + 4096;          // 4*128*16

    const int r8 = lane >> 3;
    const int gq = (lane & 7) ^ r8;

    f32x4 acc[2][4] = {};

    for (int ck = 0; ck < 4; ck++) {
        const int d0 = ck * 64;
        for (int it = wid; it < 24; it += 4) {
            if (it < 8) {
                const unsigned short* g =
                    attn16 + ((size_t)b * 256 + cB + it * 8 + r8) * 256 + d0 + gq * 8;
                GLDS(g, As + it * 512);
            } else {
                int j = it - 8;            // 0..15
                int u = j >> 2, part = j & 3;
                const unsigned short* g =
                    yhiT + (((size_t)b * 16 + ck * 4 + u) * 4096 + nB + part * 32) * 16 + lane * 8;
                GLDS(g, Bs + (u * 128 + part * 32) * 16);
            }
        }
        __syncthreads();

#pragma unroll
        for (int kwin = 0; kwin < 2; kwin++) {
            const int cc = (((kwin * 4 + q) ^ (ln & 7))) * 8;
            const int gK = kwin * 4 + q;
            half8 af[2], bfr[4];
#pragma unroll
            for (int mi = 0; mi < 2; mi++)
                af[mi] = *(const half8*)&As[(wm * 32 + mi * 16 + ln) * 64 + cc];
#pragma unroll
            for (int ni = 0; ni < 4; ni++) {
                int row = wn * 64 + ni * 16 + ln;
                bfr[ni] = *(const half8*)&Bs[(gK >> 1) * 2048 + row * 16 + (gK & 1) * 8];
            }
#pragma unroll
            for (int mi = 0; mi < 2; mi++)
#pragma unroll
                for (int ni = 0; ni < 4; ni++)
                    acc[mi][ni] = __builtin_amdgcn_mfma_f32_16x16x32_f16(
                        af[mi], bfr[ni], acc[mi][ni], 0, 0, 0);
        }
        __syncthreads();
    }

    // epilogue: acc -> padded fp32 LDS tile -> float4 residual + store
    float* os = (float*)smem;
#pragma unroll
    for (int mi = 0; mi < 2; mi++)
#pragma unroll
        for (int ni = 0; ni < 4; ni++) {
            f32x4 a = acc[mi][ni];
            int cl = wm * 32 + mi * 16 + q * 4;
            int nl = wn * 64 + ni * 16 + ln;
            os[(cl + 0) * 132 + nl] = a.x;
            os[(cl + 1) * 132 + nl] = a.y;
            os[(cl + 2) * 132 + nl] = a.z;
            os[(cl + 3) * 132 + nl] = a.w;
        }
    __syncthreads();

#pragma unroll
    for (int j = 0; j < 8; j++) {
        int u  = j * 256 + tid;          // 2048 float4 units
        int c  = u >> 5;                 // 0..63
        int nq = (u & 31) * 4;           // 0..124
        float4 ov = *(const float4*)&os[c * 132 + nq];
        size_t go = ((size_t)b * C1 + cB + c) * NN + nB + nq;
        float4 xv = *(const float4*)&x[go];
        float4 o4;
        o4.x = ov.x + xv.x; o4.y = ov.y + xv.y;
        o4.z = ov.z + xv.z; o4.w = ov.w + xv.w;
        *(float4*)&out[go] = o4;
    }
}

// ---------------------------------------------------------------------------
extern "C" void kernel_launch(void* const* d_in, const int* in_sizes, int n_in,
                              void* d_out, int out_size, void* d_ws, size_t ws_size,
                              hipStream_t stream)
{
    const float* x  = (const float*)d_in[0];
    const float* w1 = (const float*)d_in[1];
    const float* g1 = (const float*)d_in[2];
    const float* b1 = (const float*)d_in[3];
    const float* m1 = (const float*)d_in[4];
    const float* v1 = (const float*)d_in[5];
    const float* w2 = (const float*)d_in[6];
    const float* g2 = (const float*)d_in[7];
    const float* b2 = (const float*)d_in[8];
    const float* m2 = (const float*)d_in[9];
    const float* v2 = (const float*)d_in[10];
    float* out = (float*)d_out;

    // workspace (86.6 MB total):
    //  xh [17,301,504 us] -- dead after conv1, REUSED as y_hi [16,777,216 us]
    //  y1h [8,650,752 us] -- dead after conv2, REUSED as sc0..sc2 (fp32
    //    split-K partials, 3 x 1,048,576 floats = 6,291,456 us) + attn16
    //    (1,048,576 us) = 7,340,032 us <= 8,650,752 ✓
    unsigned short* xh   = (unsigned short*)d_ws;
    unsigned short* y1h  = xh  + (size_t)17301504;
    unsigned short* wt1  = y1h + (size_t)8650752;
    unsigned short* wt2  = wt1 + (size_t)294912;
    unsigned short* yhiT = wt2 + (size_t)294912;
    unsigned short* yhi  = xh;                         // alias (xh dead)
    float*          sc   = (float*)y1h;                // alias (y1h dead)
    unsigned short* attn16 = (unsigned short*)(sc + 3145728);

    // pre-pass
    nchw_to_nhwc_f16<<<dim3(C1 / 64, 66, BB), 256, 0, stream>>>(x, xh, C1);
    prep_kernel<<<2560, 256, 0, stream>>>(w1, w2, wt1, wt2, y1h);

    // conv1: 256 -> 128, chunked half-split fp16 NHWC out (padded rows)
    conv_mfma_kernel<<<dim3(CHD / 64, 8, BB), 512, 0, stream>>>(
        xh, wt1, g1, b1, m1, v1, y1h, nullptr, nullptr, C1, CHD);
    // conv2: 128 -> 256, y_hi NCHW + yhiT chunked NHWC (overwrites xh region)
    conv_mfma_kernel<<<dim3(C1 / 64, 8, BB), 512, 0, stream>>>(
        y1h, wt2, g2, b2, m2, v2, nullptr, yhi, yhiT, CHD, C1);

    // attention: split-K x3 symmetric fp16 MFMA scores -> softmax(sum thirds)
    // -> fp16 MFMA PV + float4 residual
    scores_mfma_kernel<<<dim3(10, 3, BB), 256, 0, stream>>>(yhi, sc);
    softmax_kernel<<<dim3(BB * C1), 64, 0, stream>>>(sc, attn16);
    out_mfma_kernel<<<dim3(NN / 128, 4, BB), 256, 0, stream>>>(attn16, yhiT, x, out);
}